// Round 2
// baseline (389.461 us; speedup 1.0000x reference)
//
#include <hip/hip_runtime.h>
#include <hip/hip_bf16.h>
#include <stdint.h>

// Problem constants: E=512, H=8, hd=64, T=1024, B=16, N=B*H=128, S=1025
typedef __bf16 bf16;
typedef __bf16 bf16x8 __attribute__((ext_vector_type(8)));
typedef __bf16 bf16x4 __attribute__((ext_vector_type(4)));
typedef float  f32x4  __attribute__((ext_vector_type(4)));

#define MFMA_BF16(a,b,c) __builtin_amdgcn_mfma_f32_16x16x32_bf16((a),(b),(c),0,0,0)

// ---- workspace byte offsets (total ~86.6 MB) ----
#define WS_QBF_IN  0L            // 16777216  query bf16 [r=(t,b)][e]   (reused as A2 later)
#define WS_WBF     16777216L     // 1572864   mutated in_proj_weight bf16 [f][e]
#define WS_OUTWBF  18350080L     // 524288    out_w bf16 [e][e']
#define WS_Q       18874368L     // 16777216  q*0.125 bf16 [n][t][d]
#define WS_K       35651584L     // 16777216  k bf16 [n][s<1024][d]
#define WS_V       52428800L     // 16777216  v bf16 [n][s<1024][d]
#define WS_VT      69206016L     // 16777216  v^T bf16 [n][d][s<1024]
#define WS_AWLAST  85983232L     // 524288    fp32 aw[:, :, 1024] as [n][t]
#define WS_VCS     86507520L     // 32768     fp32 col-sum of v (incl bias row) [n][d]
#define WS_MM      86540288L     // 8         {min,max} ordered-uint

__device__ __forceinline__ void gload16(const void* g, void* l) {
  __builtin_amdgcn_global_load_lds((const __attribute__((address_space(1))) uint32_t*)g,
                                   (__attribute__((address_space(3))) uint32_t*)l, 16, 0, 0);
}
__device__ __forceinline__ unsigned ordf(float x) {
  unsigned b = __float_as_uint(x);
  return (b & 0x80000000u) ? ~b : (b | 0x80000000u);
}
__device__ __forceinline__ float deordf(unsigned u) {
  unsigned b = (u & 0x80000000u) ? (u ^ 0x80000000u) : ~u;
  return __uint_as_float(b);
}

// ---------------- small prep kernels ----------------
__global__ __launch_bounds__(256) void cvt_query_kernel(const float* __restrict__ in,
                                                        bf16* __restrict__ out) {
  long i = (long)blockIdx.x * 256 + threadIdx.x;       // float4 index, n4 = 2097152
  for (; i < 2097152L; i += (long)gridDim.x * 256) {
    float4 v = ((const float4*)in)[i];
    bf16x4 o; o[0] = (bf16)v.x; o[1] = (bf16)v.y; o[2] = (bf16)v.z; o[3] = (bf16)v.w;
    ((bf16x4*)out)[i] = o;
  }
}

__global__ __launch_bounds__(256) void prep_weights_kernel(
    const float* __restrict__ in_w, const float* __restrict__ i_proj,
    const float* __restrict__ out_w, bf16* __restrict__ w_bf,
    bf16* __restrict__ outw_bf, float* __restrict__ w_ret,
    unsigned* __restrict__ mm) {
  long idx = (long)blockIdx.x * 256 + threadIdx.x;   // total 1048576
  if (idx == 0) { mm[0] = 0xFFFFFFFFu; mm[1] = 0u; } // min-slot, max-slot
  if (idx < 786432L) {
    int f = (int)(idx >> 9), e = (int)(idx & 511);
    float val = (e % 3 == 0) ? i_proj[f] : in_w[idx];
    w_bf[idx] = (bf16)val;
    // w_ret[m][i=e][j=f%512] = w[f][e]
    w_ret[(long)(f >> 9) * 262144 + (long)e * 512 + (f & 511)] = val;
  } else if (idx < 1048576L) {
    long j = idx - 786432L;
    outw_bf[j] = (bf16)out_w[j];
  }
}

// ---------------- MFMA GEMM: D[r][f] = sum_k A[r][k]*B[f][k] + bias[f] ----------------
// MODE 0: proj (N=1536) -> scatter q(scaled)/k/v bf16.  MODE 1: out-proj (N=512) -> fp32 rows.
template <int MODE>
__global__ __launch_bounds__(256, 2) void gemm_kernel(
    const bf16* __restrict__ A, const bf16* __restrict__ B,
    const float* __restrict__ bias,
    bf16* __restrict__ q_out, bf16* __restrict__ k_out, bf16* __restrict__ v_out,
    float* __restrict__ outC) {
  const int K = 512;
  __shared__ __align__(16) bf16 aTile[128 * 32];
  __shared__ __align__(16) bf16 bTile[128 * 32];
  const int tid = threadIdx.x;
  const int lane = tid & 63, w = tid >> 6;
  const int l15 = lane & 15, l4 = lane >> 4;
  const long r0 = (long)blockIdx.y * 128;
  const long f0 = (long)blockIdx.x * 128;
  const int rm = (w >> 1) * 64, cn = (w & 1) * 64;
  const int srow = tid >> 2;   // 0..63
  const int scc = tid & 3;     // chunk 0..3 (16B chunks, 4 per 32-elem row)
  f32x4 acc[4][4] = {};

  for (int kk = 0; kk < K; kk += 32) {
#pragma unroll
    for (int i = 0; i < 2; ++i) {   // A tile: 128 rows x 32 cols
      int row = srow + i * 64;
      int cc = scc ^ (row & 3);     // pre-swizzled source -> swizzled LDS layout
      gload16(A + (r0 + row) * K + kk + cc * 8, (char*)aTile + (w * 64 + i * 256) * 16);
    }
#pragma unroll
    for (int i = 0; i < 2; ++i) {   // B tile
      int row = srow + i * 64;
      int cc = scc ^ (row & 3);
      gload16(B + (f0 + row) * K + kk + cc * 8, (char*)bTile + (w * 64 + i * 256) * 16);
    }
    __syncthreads();
    bf16x8 af[4], bfr[4];
#pragma unroll
    for (int mi = 0; mi < 4; ++mi) {
      int r = rm + mi * 16 + l15;
      int c = l4 ^ (r & 3);
      af[mi] = *(const bf16x8*)((const char*)aTile + r * 64 + c * 16);
    }
#pragma unroll
    for (int ni = 0; ni < 4; ++ni) {
      int r = cn + ni * 16 + l15;
      int c = l4 ^ (r & 3);
      bfr[ni] = *(const bf16x8*)((const char*)bTile + r * 64 + c * 16);
    }
#pragma unroll
    for (int mi = 0; mi < 4; ++mi)
#pragma unroll
      for (int ni = 0; ni < 4; ++ni)
        acc[mi][ni] = MFMA_BF16(af[mi], bfr[ni], acc[mi][ni]);
    __syncthreads();
  }
  // epilogue: C/D layout col=lane&15, row=(lane>>4)*4+reg  [verified m89/m91]
#pragma unroll
  for (int mi = 0; mi < 4; ++mi)
#pragma unroll
    for (int ni = 0; ni < 4; ++ni)
#pragma unroll
      for (int r = 0; r < 4; ++r) {
        long row = r0 + rm + mi * 16 + l4 * 4 + r;
        int f = (int)f0 + cn + ni * 16 + l15;
        float val = acc[mi][ni][r] + bias[f];
        if (MODE == 0) {
          int t = (int)(row >> 4), b = (int)(row & 15);
          int which = f >> 9, hh = (f >> 6) & 7, d = f & 63;
          long off = ((long)(b * 8 + hh) * 1024 + t) * 64 + d;
          if (which == 0)      q_out[off] = (bf16)(val * 0.125f);
          else if (which == 1) k_out[off] = (bf16)val;
          else                 v_out[off] = (bf16)val;
        } else {
          outC[row * 512 + f] = val;
        }
      }
}

// ---------------- V transpose: vT[n][d][s] = v[n][s][d] ----------------
__global__ __launch_bounds__(256) void transpose_v_kernel(const bf16* __restrict__ v_bf,
                                                          bf16* __restrict__ vT) {
  const int n = blockIdx.y;
  const long s0 = (long)blockIdx.x * 64;
  __shared__ __align__(16) bf16 tile[64][72];
  const int tid = threadIdx.x;
  const int row = tid >> 3, cc = tid & 7;
#pragma unroll
  for (int it = 0; it < 2; ++it) {
    int r = row + it * 32;
    bf16x8 vv = *(const bf16x8*)(v_bf + ((long)n * 1024 + s0 + r) * 64 + cc * 8);
    *(bf16x8*)&tile[r][cc * 8] = vv;
  }
  __syncthreads();
#pragma unroll
  for (int it = 0; it < 2; ++it) {
    int d = row + it * 32;
    bf16x8 ov;
#pragma unroll
    for (int j = 0; j < 8; ++j) ov[j] = tile[cc * 8 + j][d];
    *(bf16x8*)(vT + ((long)n * 64 + d) * 1024 + s0 + cc * 8) = ov;
  }
}

// ---------------- v column sum (incl bias_v row) ----------------
__global__ __launch_bounds__(256) void vcolsum_kernel(const bf16* __restrict__ v_bf,
                                                      const float* __restrict__ bias_v,
                                                      float* __restrict__ vcs) {
  const int n = blockIdx.x, h = n & 7;
  const int d = threadIdx.x & 63, g = threadIdx.x >> 6;
  float acc = 0.f;
  const bf16* base = v_bf + (long)n * 65536 + d;
  for (int s = g * 256; s < g * 256 + 256; ++s) acc += (float)base[(long)s * 64];
  __shared__ float red[4][64];
  red[g][d] = acc;
  __syncthreads();
  if (g == 0) vcs[n * 64 + d] = red[0][d] + red[1][d] + red[2][d] + red[3][d] + bias_v[h * 64 + d];
}

// ---------------- fused scores: QK^T, min/max, head-sum, PV ----------------
// block: (b, t-tile of 32); 8 waves = 8 heads; s-tiles of 64 over s<1024.
__global__ __launch_bounds__(512, 2) void attn_stage2_kernel(
    const bf16* __restrict__ q_bf, const bf16* __restrict__ k_bf,
    const bf16* __restrict__ vT, float* __restrict__ attn_un /* = out_attn slot */,
    float* __restrict__ awsum /* d_out aw_avg slot */, unsigned* __restrict__ mm) {
  __shared__ __align__(16) bf16 qs[8 * 32 * 64];    // 32KB  [h][t][d], chunk^=(t&7)
  __shared__ __align__(16) bf16 kvs[8 * 64 * 64];   // 64KB  k:[h][s][d] / vT:[h][d][s]
  __shared__ __align__(16) bf16 aws[8 * 32 * 64];   // 32KB  [h][t][s], byte^((t&7)<<4)
  const int tid = threadIdx.x;
  const int lane = tid & 63, w = tid >> 6, h = w;
  const int l15 = lane & 15, l4 = lane >> 4;
  const int b = blockIdx.y;
  const int t0 = blockIdx.x * 32;

  // stage q once (pre-swizzled source -> linear LDS)
#pragma unroll
  for (int i = 0; i < 4; ++i) {
    int c = tid + i * 512;                 // chunk 0..2047
    int hh = c >> 8, t = (c >> 3) & 31, cc = c & 7;
    int cc2 = cc ^ (t & 7);
    gload16(q_bf + ((long)(b * 8 + hh) * 1024 + t0 + t) * 64 + cc2 * 8,
            (char*)qs + w * 1024 + i * 8192);
  }

  float vmin = 1e30f, vmax = -1e30f;
  f32x4 pv[2][4] = {};

  for (int st = 0; st < 16; ++st) {
    const int s0 = st * 64;
    // stage K tile
#pragma unroll
    for (int i = 0; i < 8; ++i) {
      int c = tid + i * 512;               // chunk 0..4095
      int hh = c >> 9, s = (c >> 3) & 63, cc = c & 7;
      int cc2 = cc ^ (s & 7);
      gload16(k_bf + ((long)(b * 8 + hh) * 1024 + s0 + s) * 64 + cc2 * 8,
              (char*)kvs + w * 1024 + i * 8192);
    }
    __syncthreads();
    // QK^T  aw[t][s] = sum_d q*k
    f32x4 aw[2][4] = {};
#pragma unroll
    for (int kd = 0; kd < 64; kd += 32) {
      bf16x8 af[2], bfr[4];
#pragma unroll
      for (int mi = 0; mi < 2; ++mi) {
        int t = mi * 16 + l15;
        int c = ((kd >> 3) + l4) ^ (t & 7);
        af[mi] = *(const bf16x8*)((const char*)qs + h * 4096 + t * 128 + c * 16);
      }
#pragma unroll
      for (int ni = 0; ni < 4; ++ni) {
        int s = ni * 16 + l15;
        int c = ((kd >> 3) + l4) ^ (s & 7);
        bfr[ni] = *(const bf16x8*)((const char*)kvs + h * 8192 + s * 128 + c * 16);
      }
#pragma unroll
      for (int mi = 0; mi < 2; ++mi)
#pragma unroll
        for (int ni = 0; ni < 4; ++ni)
          aw[mi][ni] = MFMA_BF16(af[mi], bfr[ni], aw[mi][ni]);
    }
    // min/max + stash aw tile to LDS (bf16, swizzled)
#pragma unroll
    for (int mi = 0; mi < 2; ++mi)
#pragma unroll
      for (int ni = 0; ni < 4; ++ni)
#pragma unroll
        for (int r = 0; r < 4; ++r) {
          float v = aw[mi][ni][r];
          vmin = fminf(vmin, v); vmax = fmaxf(vmax, v);
          int t = mi * 16 + l4 * 4 + r, s = ni * 16 + l15;
          long bo = (long)((h * 4096 + t * 128 + s * 2) ^ ((t & 7) << 4));
          *(bf16*)((char*)aws + bo) = (bf16)v;
        }
    __syncthreads();
    // stage vT tile into kvs
#pragma unroll
    for (int i = 0; i < 8; ++i) {
      int c = tid + i * 512;
      int hh = c >> 9, d = (c >> 3) & 63, cc = c & 7;
      int cc2 = cc ^ (d & 7);
      gload16(vT + ((long)(b * 8 + hh) * 64 + d) * 1024 + s0 + cc2 * 8,
              (char*)kvs + w * 1024 + i * 8192);
    }
    __syncthreads();
    // head-sum -> aw_avg slot (raw sums; rescaled later)
#pragma unroll
    for (int it = 0; it < 4; ++it) {
      int idx = tid + it * 512;            // 0..2047 = 32x64
      int i = idx >> 6, j = idx & 63;
      float ssum = 0.f;
#pragma unroll
      for (int hh = 0; hh < 8; ++hh) {
        long bo = (long)((hh * 4096 + i * 128 + j * 2) ^ ((i & 7) << 4));
        ssum += (float)*(const bf16*)((const char*)aws + bo);
      }
      awsum[((long)b * 1024 + t0 + i) * 1025 + s0 + j] = ssum;
    }
    // PV: pv[t][d] += sum_s aw[t][s] * v[s][d]   (B from vT rows)
#pragma unroll
    for (int kd = 0; kd < 64; kd += 32) {
      bf16x8 af[2], bfr[4];
#pragma unroll
      for (int mi = 0; mi < 2; ++mi) {
        int t = mi * 16 + l15;
        int c = ((kd >> 3) + l4) ^ (t & 7);
        af[mi] = *(const bf16x8*)((const char*)aws + h * 4096 + t * 128 + c * 16);
      }
#pragma unroll
      for (int ni = 0; ni < 4; ++ni) {
        int d = ni * 16 + l15;
        int c = ((kd >> 3) + l4) ^ (d & 7);
        bfr[ni] = *(const bf16x8*)((const char*)kvs + h * 8192 + d * 128 + c * 16);
      }
#pragma unroll
      for (int mi = 0; mi < 2; ++mi)
#pragma unroll
        for (int ni = 0; ni < 4; ++ni)
          pv[mi][ni] = MFMA_BF16(af[mi], bfr[ni], pv[mi][ni]);
    }
    __syncthreads();
  }
  // write PV accumulator (unnormalized, into out_attn scratch slot)
  const long n = (long)b * 8 + h;
#pragma unroll
  for (int mi = 0; mi < 2; ++mi)
#pragma unroll
    for (int ni = 0; ni < 4; ++ni)
#pragma unroll
      for (int r = 0; r < 4; ++r) {
        int t = mi * 16 + l4 * 4 + r, d = ni * 16 + l15;
        attn_un[(n * 1024 + t0 + t) * 64 + d] = pv[mi][ni][r];
      }
  // block min/max -> global atomics
#pragma unroll
  for (int off = 32; off; off >>= 1) {
    vmin = fminf(vmin, __shfl_xor(vmin, off));
    vmax = fmaxf(vmax, __shfl_xor(vmax, off));
  }
  if (lane == 0) { atomicMin(&mm[0], ordf(vmin)); atomicMax(&mm[1], ordf(vmax)); }
}

// ---------------- bias column s=1024: aw_last[n][t] = q[n][t][:] . bias_k[h] ----------------
__global__ __launch_bounds__(256) void bias_col_kernel(const bf16* __restrict__ q_bf,
                                                       const float* __restrict__ bias_k,
                                                       float* __restrict__ aw_last,
                                                       unsigned* __restrict__ mm) {
  const int n = blockIdx.y, h = n & 7;
  const int t = blockIdx.x * 256 + threadIdx.x;
  float acc = 0.f;
  const bf16* qrow = q_bf + ((long)n * 1024 + t) * 64;
#pragma unroll
  for (int j = 0; j < 8; ++j) {
    bf16x8 qv = *(const bf16x8*)(qrow + j * 8);
#pragma unroll
    for (int e = 0; e < 8; ++e) acc += (float)qv[e] * bias_k[h * 64 + j * 8 + e];
  }
  aw_last[(long)n * 1024 + t] = acc;
  float vmin = acc, vmax = acc;
#pragma unroll
  for (int off = 32; off; off >>= 1) {
    vmin = fminf(vmin, __shfl_xor(vmin, off));
    vmax = fmaxf(vmax, __shfl_xor(vmax, off));
  }
  if ((threadIdx.x & 63) == 0) { atomicMin(&mm[0], ordf(vmin)); atomicMax(&mm[1], ordf(vmax)); }
}

// ---------------- affine-combine -> A2 bf16 [r=(t,b)][e'=(h,d)] ----------------
__global__ __launch_bounds__(256) void convertA_kernel(
    const float* __restrict__ attn_un, const float* __restrict__ aw_last,
    const float* __restrict__ vcs, const float* __restrict__ bias_v,
    const unsigned* __restrict__ mm, bf16* __restrict__ A2) {
  long idx = (long)blockIdx.x * 256 + threadIdx.x;   // 0..8388607
  float mn = deordf(mm[0]), mx = deordf(mm[1]);
  float a = 1.f / (mx - mn), c = -mn * a;
  int col = (int)(idx & 511);
  long r = idx >> 9;
  int t = (int)(r >> 4), b = (int)(r & 15);
  int h = col >> 6, d = col & 63;
  long n = (long)b * 8 + h;
  float val = attn_un[(n * 1024 + t) * 64 + d] + aw_last[n * 1024 + t] * bias_v[col];
  val = a * val + c * vcs[n * 64 + d];
  A2[idx] = (bf16)val;
}

// ---------------- final aw_avg rescale (in place in d_out) ----------------
__global__ __launch_bounds__(256) void rescale_kernel(float* __restrict__ aw_out,
                                                      const float* __restrict__ aw_last,
                                                      const unsigned* __restrict__ mm) {
  long idx = (long)blockIdx.x * 256 + threadIdx.x;   // 0..16793599
  float mn = deordf(mm[0]), mx = deordf(mm[1]);
  float a = 1.f / (mx - mn), c = -mn * a;
  int s = (int)(idx % 1025);
  long bt = idx / 1025;
  float v;
  if (s < 1024) {
    v = aw_out[idx];
  } else {
    int b = (int)(bt >> 10), t = (int)(bt & 1023);
    v = 0.f;
#pragma unroll
    for (int h = 0; h < 8; ++h) v += aw_last[(long)(b * 8 + h) * 1024 + t];
  }
  aw_out[idx] = a * (v * 0.125f) + c;
}

// ---------------- launcher ----------------
extern "C" void kernel_launch(void* const* d_in, const int* in_sizes, int n_in,
                              void* d_out, int out_size, void* d_ws, size_t ws_size,
                              hipStream_t stream) {
  const float* query  = (const float*)d_in[0];
  const float* i_proj = (const float*)d_in[1];
  const float* in_w   = (const float*)d_in[2];
  const float* in_b   = (const float*)d_in[3];
  const float* out_w  = (const float*)d_in[4];
  const float* out_b  = (const float*)d_in[5];
  const float* bias_k = (const float*)d_in[6];
  const float* bias_v = (const float*)d_in[7];
  float* out = (float*)d_out;

  char* ws = (char*)d_ws;
  bf16* qbf_in = (bf16*)(ws + WS_QBF_IN);
  bf16* w_bf   = (bf16*)(ws + WS_WBF);
  bf16* outwbf = (bf16*)(ws + WS_OUTWBF);
  bf16* q_bf   = (bf16*)(ws + WS_Q);
  bf16* k_bf   = (bf16*)(ws + WS_K);
  bf16* v_bf   = (bf16*)(ws + WS_V);
  bf16* vT     = (bf16*)(ws + WS_VT);
  float* aw_last = (float*)(ws + WS_AWLAST);
  float* vcs     = (float*)(ws + WS_VCS);
  unsigned* mm   = (unsigned*)(ws + WS_MM);
  bf16* A2 = qbf_in;  // reuse: qbf_in dead after proj GEMM

  float* out_attn  = out;                       // (1024,16,512); also PV scratch
  float* out_awavg = out + 8388608L;            // (16,1024,1025)
  float* out_wret  = out + 25182208L;           // (3,512,512)
  float* attn_un = out_attn;                    // unnormalized PV staged in out slot

  cvt_query_kernel<<<2048, 256, 0, stream>>>(query, qbf_in);
  prep_weights_kernel<<<4096, 256, 0, stream>>>(in_w, i_proj, out_w, w_bf, outwbf, out_wret, mm);
  gemm_kernel<0><<<dim3(12, 128), 256, 0, stream>>>(qbf_in, w_bf, in_b, q_bf, k_bf, v_bf, nullptr);
  transpose_v_kernel<<<dim3(16, 128), 256, 0, stream>>>(v_bf, vT);
  vcolsum_kernel<<<128, 256, 0, stream>>>(v_bf, bias_v, vcs);
  attn_stage2_kernel<<<dim3(32, 16), 512, 0, stream>>>(q_bf, k_bf, vT, attn_un, out_awavg, mm);
  bias_col_kernel<<<dim3(4, 128), 256, 0, stream>>>(q_bf, bias_k, aw_last, mm);
  convertA_kernel<<<32768, 256, 0, stream>>>(attn_un, aw_last, vcs, bias_v, mm, A2);
  gemm_kernel<1><<<dim3(4, 128), 256, 0, stream>>>(A2, outwbf, out_b, nullptr, nullptr, nullptr, out_attn);
  rescale_kernel<<<65600, 256, 0, stream>>>(out_awavg, aw_last, mm);
}